// Round 2
// baseline (473.475 us; speedup 1.0000x reference)
//
#include <hip/hip_runtime.h>

// Problem constants: x,y are (16, 64, 256, 256) fp32.
#define NB 16
#define C  64
#define HW 65536          // 256*256
#define HW4 (HW / 4)      // float4 per row (16384)
#define Q4  (HW4 / 4)     // float4 per quarter row (4096)

// clang extended vector => works with __builtin_nontemporal_load/store
typedef float f32x4 __attribute__((ext_vector_type(4)));

// ---------------------------------------------------------------------------
// Kernel 1: quarter-row partial sums of y.
// 4096 blocks = (row, quarter). 64 KiB contiguous stream per block, 16
// iterations/thread (unroll 8 -> ~50 VGPR), launch_bounds(256,8) forces
// VGPR<=64 so 8 blocks/CU (32 waves/CU, max occupancy) stay resident.
// NT loads: y has zero reuse and the 1 GiB ws-poison just flushed the caches.
// ---------------------------------------------------------------------------
__global__ __launch_bounds__(256, 8) void mean_kernel(const float* __restrict__ y,
                                                      float* __restrict__ part) {
    const int blk = blockIdx.x;                 // row*4 + q, row = b*64 + c
    const f32x4* y4 = (const f32x4*)y + (size_t)blk * Q4;
    const int tid = threadIdx.x;

    f32x4 acc = {0.f, 0.f, 0.f, 0.f};
    #pragma unroll 8
    for (int k = tid; k < Q4; k += 256) {       // 16 iterations/thread
        acc += __builtin_nontemporal_load(y4 + k);
    }
    float s = (acc.x + acc.y) + (acc.z + acc.w);

    // wave-64 shuffle reduce
    #pragma unroll
    for (int off = 32; off > 0; off >>= 1)
        s += __shfl_down(s, off, 64);

    __shared__ float smem[4];
    if ((tid & 63) == 0) smem[tid >> 6] = s;
    __syncthreads();
    if (tid == 0)
        part[blk] = (smem[0] + smem[1]) + (smem[2] + smem[3]);  // raw sum
}

// ---------------------------------------------------------------------------
// Kernel 2: out[b,i] = sum_c x[b,c,i] * wm[b,c], wm = combined+scaled partials.
// 2048 blocks = (b, 128-float4 chunk) x 256 threads. The c-reduction is split
// across thread-halves (t<128: c in [0,32); t>=128: c in [32,64)) so each
// thread issues only 32 NT loads (shorter serial chain), combined via one LDS
// round-trip. launch_bounds(256,6) caps VGPR<=84 -> 6 blocks/CU = 24 waves/CU
// (up from 16) for latency hiding.
// ---------------------------------------------------------------------------
__global__ __launch_bounds__(256, 6) void gemv_kernel(const float* __restrict__ x,
                                                      const float* __restrict__ part,
                                                      float* __restrict__ out) {
    const int b     = blockIdx.x >> 7;           // 128 blocks per batch
    const int chunk = blockIdx.x & 127;          // 128 float4 columns per chunk
    const int t     = threadIdx.x;
    const int col   = (chunk << 7) + (t & 127);  // float4 idx in [0, HW4)
    const int ch    = t >> 7;                    // c-half: 0 or 1 (wave-uniform)

    __shared__ float ps[256];
    __shared__ float ws[C];
    ps[t] = part[(b << 8) + t];                  // b*256 + c*4 + q
    __syncthreads();
    if (t < C) {
        // fold mean (2^-16) AND final scale (2^-22): both exact pow2 -> bit-exact
        ws[t] = ((ps[4 * t] + ps[4 * t + 1]) + (ps[4 * t + 2] + ps[4 * t + 3]))
                * (1.0f / HW) * (1.0f / ((float)HW * (float)C));
    }
    __syncthreads();

    const f32x4* xb = (const f32x4*)x + (size_t)b * (C * (size_t)HW4)
                      + (size_t)(ch << 5) * HW4 + col;

    f32x4 acc = {0.f, 0.f, 0.f, 0.f};
    #pragma unroll 8
    for (int d = 0; d < 32; ++d) {
        f32x4 v = __builtin_nontemporal_load(xb + (size_t)d * HW4);
        acc += v * ws[(ch << 5) + d];
    }

    __shared__ f32x4 sacc[128];
    if (ch == 1) sacc[t & 127] = acc;
    __syncthreads();
    if (ch == 0) {
        f32x4 o = acc + sacc[t];
        __builtin_nontemporal_store(o, (f32x4*)out + (size_t)b * HW4 + col);
    }
}

extern "C" void kernel_launch(void* const* d_in, const int* in_sizes, int n_in,
                              void* d_out, int out_size, void* d_ws, size_t ws_size,
                              hipStream_t stream) {
    const float* x = (const float*)d_in[0];
    const float* y = (const float*)d_in[1];
    float* out = (float*)d_out;
    float* part = (float*)d_ws;   // 4096 floats = 16 KiB scratch

    mean_kernel<<<dim3(NB * C * 4), dim3(256), 0, stream>>>(y, part);
    gemv_kernel<<<dim3(NB * 128), dim3(256), 0, stream>>>(x, part, out);
}